// Round 1
// baseline (315.075 us; speedup 1.0000x reference)
//
#include <hip/hip_runtime.h>
#include <math.h>

#define GAMMA 0.1f
#define TAU   0.01f
#define NN    256
#define MM    512
#define KK    512

__device__ __forceinline__ float sigmoidf(float v) {
    return 1.0f / (1.0f + __expf(-v));
}
__device__ __forceinline__ float dot4(float4 a, float4 b) {
    return a.x * b.x + a.y * b.y + a.z * b.z + a.w * b.w;
}

// ---------------------------------------------------------------------------
// Kernel 1: x_new (256x256 + 256x512 GEMVs), phi_xn = sigmoid(x_new) -> ws[0:256],
//           psi_z = tanh(z) -> ws[256:768]
// grid = 6 blocks x 256 threads. blocks 0..3: x_new rows (wave-per-row, 16 rows/wave).
// blocks 4..5: psi_z.
// ---------------------------------------------------------------------------
__global__ __launch_bounds__(256) void k_state(
    const float* __restrict__ I, const float* __restrict__ x,
    const float* __restrict__ W, const float* __restrict__ z,
    const float* __restrict__ Win1,
    float* __restrict__ out, float* __restrict__ ws)
{
    const int b = blockIdx.x, t = threadIdx.x;
    if (b < 4) {
        const int wave = t >> 6, lane = t & 63;
        // per-lane loop invariants: phi(x[4l..4l+3]) and I[4l..], I[256+4l..]
        float4 xv = ((const float4*)x)[lane];
        float4 ph = make_float4(sigmoidf(xv.x), sigmoidf(xv.y),
                                sigmoidf(xv.z), sigmoidf(xv.w));
        float4 i0 = ((const float4*)I)[lane];
        float4 i1 = ((const float4*)I)[64 + lane];
        const int row0 = b * 64 + wave * 16;
        for (int r = 0; r < 16; ++r) {
            const int row = row0 + r;
            float4 wv = ((const float4*)(W + row * NN))[lane];
            float4 a0 = ((const float4*)(Win1 + row * KK))[lane];
            float4 a1 = ((const float4*)(Win1 + row * KK))[64 + lane];
            float acc = GAMMA * dot4(wv, ph) + dot4(a0, i0) + dot4(a1, i1);
#pragma unroll
            for (int m = 32; m; m >>= 1) acc += __shfl_xor(acc, m, 64);
            if (lane == 0) {
                float xn = (1.0f - GAMMA) * x[row] + acc;
                out[row] = xn;              // x_new output
                ws[row] = sigmoidf(xn);     // phi_xn
            }
        }
    } else {
        const int idx = (b - 4) * 256 + t;
        ws[NN + idx] = tanhf(z[idx]);       // psi_z
    }
}

// ---------------------------------------------------------------------------
// Kernel 2 (fused): blocks 0..511 -> z_new row b (H GEMV, 256KB/row);
// blocks 512..4607 -> 16 rows of W_new each (D GEMV, wave-per-row).
// ws: [0:256]=phi_xn, [256:768]=psi_z.
// ---------------------------------------------------------------------------
__global__ __launch_bounds__(256) void k_big(
    const float* __restrict__ W, const float* __restrict__ Cv,
    const float* __restrict__ D, const float* __restrict__ F,
    const float* __restrict__ H, const float* __restrict__ Win2,
    const float* __restrict__ I, const float* __restrict__ z,
    const float* __restrict__ ws, float* __restrict__ out)
{
    __shared__ float sm[768];
    __shared__ float red[4];
    const int b = blockIdx.x, t = threadIdx.x;

    if (b < MM) {
        // ---- z_new row b: acc = H[b,:] @ Phi + W_in_2[b,:] @ I ----
        if (t < 64) ((float4*)sm)[t] = ((const float4*)ws)[t];   // phi_xn, 256 floats
        __syncthreads();
        const float4* H4 = (const float4*)(H + (size_t)b * (NN * NN));
        // float4 index f = t + 256q covers Phi[4f..4f+3] = phi[f>>6] * phi4[f&63].
        // f&63 == t&63 is loop-invariant; f>>6 = (t>>6) + 4q is wave-uniform.
        const float4 pj = ((const float4*)sm)[t & 63];
        const int wv4 = t >> 6;
        float acc = 0.0f;
#pragma unroll 8
        for (int q = 0; q < 64; ++q) {
            float4 h = H4[t + 256 * q];
            float pi = sm[wv4 + 4 * q];
            acc += pi * dot4(h, pj);
        }
        // + W_in_2 @ I (512 wide, 2 elems/thread) — same gamma*tau coefficient
        acc += Win2[(size_t)b * KK + t] * I[t]
             + Win2[(size_t)b * KK + 256 + t] * I[256 + t];
#pragma unroll
        for (int m = 32; m; m >>= 1) acc += __shfl_xor(acc, m, 64);
        if ((t & 63) == 0) red[t >> 6] = acc;
        __syncthreads();
        if (t == 0) {
            const float gt = GAMMA * TAU;
            float tot = red[0] + red[1] + red[2] + red[3];
            float ps = ws[NN + b];
            float zn = (1.0f - gt) * z[b] + gt * (F[b] * ps + tot);
            out[NN + NN * NN + b] = zn;
        }
    } else {
        // ---- W_new: 16 D-rows per block, 4 per wave ----
        if (t < 128)      ((float4*)sm)[t] = ((const float4*)(ws + NN))[t];  // psi_z [0:512]
        else if (t < 192) ((float4*)sm)[t] = ((const float4*)ws)[t - 128];   // phi  [512:768]
        __syncthreads();
        const int wave = t >> 6, lane = t & 63;
        const float4 z0 = ((const float4*)sm)[lane];        // psi_z[4l..4l+3]
        const float4 z1 = ((const float4*)sm)[64 + lane];   // psi_z[256+4l..]
        const int rowbase = (b - MM) * 16 + wave * 4;
        for (int r = 0; r < 4; ++r) {
            const int row = rowbase + r;                    // 0..65535
            const float4* D4 = (const float4*)(D + (size_t)row * MM);
            float acc = dot4(D4[lane], z0) + dot4(D4[64 + lane], z1);
#pragma unroll
            for (int m = 32; m; m >>= 1) acc += __shfl_xor(acc, m, 64);
            if (lane == 0) {
                float Phi = sm[512 + (row >> 8)] * sm[512 + (row & 255)];
                float wn = (1.0f - GAMMA) * W[row]
                         + GAMMA * (Cv[row] * Phi + acc);
                out[NN + row] = wn;
            }
        }
    }
}

extern "C" void kernel_launch(void* const* d_in, const int* in_sizes, int n_in,
                              void* d_out, int out_size, void* d_ws, size_t ws_size,
                              hipStream_t stream) {
    const float* I    = (const float*)d_in[0];
    const float* x    = (const float*)d_in[1];
    const float* W    = (const float*)d_in[2];
    const float* z    = (const float*)d_in[3];
    const float* C    = (const float*)d_in[4];
    const float* D    = (const float*)d_in[5];
    const float* F    = (const float*)d_in[6];
    const float* H    = (const float*)d_in[7];
    const float* Win1 = (const float*)d_in[8];
    const float* Win2 = (const float*)d_in[9];
    float* out = (float*)d_out;
    float* ws  = (float*)d_ws;   // ws[0:256]=phi_xn, ws[256:768]=psi_z (3 KB)

    hipLaunchKernelGGL(k_state, dim3(6), dim3(256), 0, stream,
                       I, x, W, z, Win1, out, ws);
    // 512 H-row blocks first (longest-running), then 4096 D blocks (16 rows each)
    hipLaunchKernelGGL(k_big, dim3(MM + (NN * NN) / 16), dim3(256), 0, stream,
                       W, C, D, F, H, Win2, I, z, ws, out);
}

// Round 2
// 297.030 us; speedup vs baseline: 1.0608x; 1.0608x over previous
//
#include <hip/hip_runtime.h>
#include <math.h>

#define GAMMA 0.1f
#define TAU   0.01f
#define NN    256
#define MM    512
#define KK    512

__device__ __forceinline__ float sigmoidf(float v) {
    return 1.0f / (1.0f + __expf(-v));
}
__device__ __forceinline__ float4 sigmoid4(float4 v) {
    return make_float4(sigmoidf(v.x), sigmoidf(v.y), sigmoidf(v.z), sigmoidf(v.w));
}
__device__ __forceinline__ float dot4(float4 a, float4 b) {
    return a.x * b.x + a.y * b.y + a.z * b.z + a.w * b.w;
}

// ---------------------------------------------------------------------------
// Kernel 1: x_new rows (blocks 0..15, 4 waves x 4 rows, all loads in flight),
//           psi_z = tanh(z) (blocks 16..17).
// ws[0:256] = phi_xn, ws[256:768] = psi_z.
// ---------------------------------------------------------------------------
__global__ __launch_bounds__(256) void k_state(
    const float* __restrict__ I, const float* __restrict__ x,
    const float* __restrict__ W, const float* __restrict__ z,
    const float* __restrict__ Win1,
    float* __restrict__ out, float* __restrict__ ws)
{
    const int b = blockIdx.x, t = threadIdx.x;
    if (b < 16) {
        const int wave = t >> 6, lane = t & 63;
        const int row0 = b * 16 + wave * 4;
        // issue ALL loads first (12 row loads + invariants), reduce after
        float4 xv = ((const float4*)x)[lane];
        float4 i0 = ((const float4*)I)[lane];
        float4 i1 = ((const float4*)I)[64 + lane];
        const float4* Wr = (const float4*)(W + row0 * NN);    // 64 f4 / row
        float4 w0 = Wr[lane], w1 = Wr[lane + 64], w2 = Wr[lane + 128], w3 = Wr[lane + 192];
        const float4* A = (const float4*)(Win1 + row0 * KK);  // 128 f4 / row
        float4 a0 = A[lane],       c0 = A[lane + 64];
        float4 a1 = A[lane + 128], c1 = A[lane + 192];
        float4 a2 = A[lane + 256], c2 = A[lane + 320];
        float4 a3 = A[lane + 384], c3 = A[lane + 448];
        float4 xo = ((const float4*)x)[row0 >> 2];            // epilogue value, early

        float4 ph = sigmoid4(xv);
        float s0 = GAMMA * dot4(w0, ph) + dot4(a0, i0) + dot4(c0, i1);
        float s1 = GAMMA * dot4(w1, ph) + dot4(a1, i0) + dot4(c1, i1);
        float s2 = GAMMA * dot4(w2, ph) + dot4(a2, i0) + dot4(c2, i1);
        float s3 = GAMMA * dot4(w3, ph) + dot4(a3, i0) + dot4(c3, i1);
#pragma unroll
        for (int m = 32; m; m >>= 1) {
            s0 += __shfl_xor(s0, m, 64);
            s1 += __shfl_xor(s1, m, 64);
            s2 += __shfl_xor(s2, m, 64);
            s3 += __shfl_xor(s3, m, 64);
        }
        if (lane == 0) {
            float4 xn;
            xn.x = (1.0f - GAMMA) * xo.x + s0;
            xn.y = (1.0f - GAMMA) * xo.y + s1;
            xn.z = (1.0f - GAMMA) * xo.z + s2;
            xn.w = (1.0f - GAMMA) * xo.w + s3;
            ((float4*)out)[row0 >> 2] = xn;          // x_new
            ((float4*)ws)[row0 >> 2] = sigmoid4(xn); // phi_xn
        }
    } else {
        const int idx = (b - 16) * 256 + t;
        ws[NN + idx] = tanhf(z[idx]);                // psi_z
    }
}

// ---------------------------------------------------------------------------
// Kernel 2 (fused): blocks 0..511 -> z_new row b (H GEMV, unroll 16);
// blocks 512..2559 -> 32 rows of W_new each (8 rows/wave, 16 loads in flight).
// ---------------------------------------------------------------------------
__global__ __launch_bounds__(256) void k_big(
    const float* __restrict__ W, const float* __restrict__ Cv,
    const float* __restrict__ D, const float* __restrict__ F,
    const float* __restrict__ H, const float* __restrict__ Win2,
    const float* __restrict__ I, const float* __restrict__ z,
    const float* __restrict__ ws, float* __restrict__ out)
{
    __shared__ float sm[768];
    __shared__ float red[4];
    const int b = blockIdx.x, t = threadIdx.x;

    if (b < MM) {
        // ---- z_new row b: H[b,:] @ Phi + W_in_2[b,:] @ I ----
        if (t < 64) ((float4*)sm)[t] = ((const float4*)ws)[t];   // phi_xn
        // hoist Win2/I loads ahead of the main loop
        float wi = Win2[(size_t)b * KK + t] * I[t]
                 + Win2[(size_t)b * KK + 256 + t] * I[256 + t];
        __syncthreads();
        const float4* H4 = (const float4*)(H + (size_t)b * (NN * NN));
        const float4 pj = ((const float4*)sm)[t & 63];
        const int wv4 = t >> 6;
        float acc = wi;
#pragma unroll 16
        for (int q = 0; q < 64; ++q) {
            float4 h = H4[t + 256 * q];
            acc += sm[wv4 + 4 * q] * dot4(h, pj);
        }
#pragma unroll
        for (int m = 32; m; m >>= 1) acc += __shfl_xor(acc, m, 64);
        if ((t & 63) == 0) red[t >> 6] = acc;
        __syncthreads();
        if (t == 0) {
            const float gt = GAMMA * TAU;
            float tot = red[0] + red[1] + red[2] + red[3];
            float zn = (1.0f - gt) * z[b] + gt * (F[b] * ws[NN + b] + tot);
            out[NN + NN * NN + b] = zn;
        }
    } else {
        // ---- W_new: 32 D-rows per block, 8 per wave, all 16 loads in flight ----
        if (t < 128)      ((float4*)sm)[t] = ((const float4*)(ws + NN))[t];  // psi_z
        else if (t < 192) ((float4*)sm)[t] = ((const float4*)ws)[t - 128];   // phi
        __syncthreads();
        const int wave = t >> 6, lane = t & 63;
        const float4 z0 = ((const float4*)sm)[lane];
        const float4 z1 = ((const float4*)sm)[64 + lane];
        const int row0 = (b - MM) * 32 + wave * 8;
        const float4* R = (const float4*)(D + (size_t)row0 * MM);  // 128 f4/row
        float4 pA = R[lane],       qA = R[lane + 64];
        float4 pB = R[lane + 128], qB = R[lane + 192];
        float4 pC = R[lane + 256], qC = R[lane + 320];
        float4 pD = R[lane + 384], qD = R[lane + 448];
        float4 pE = R[lane + 512], qE = R[lane + 576];
        float4 pF = R[lane + 640], qF = R[lane + 704];
        float4 pG = R[lane + 768], qG = R[lane + 832];
        float4 pH = R[lane + 896], qH = R[lane + 960];
        // epilogue operands, issued early (broadcast loads)
        float4 w0 = ((const float4*)W)[row0 >> 2],  w1 = ((const float4*)W)[(row0 >> 2) + 1];
        float4 c0 = ((const float4*)Cv)[row0 >> 2], c1 = ((const float4*)Cv)[(row0 >> 2) + 1];

        float s0 = dot4(pA, z0) + dot4(qA, z1);
        float s1 = dot4(pB, z0) + dot4(qB, z1);
        float s2 = dot4(pC, z0) + dot4(qC, z1);
        float s3 = dot4(pD, z0) + dot4(qD, z1);
        float s4 = dot4(pE, z0) + dot4(qE, z1);
        float s5 = dot4(pF, z0) + dot4(qF, z1);
        float s6 = dot4(pG, z0) + dot4(qG, z1);
        float s7 = dot4(pH, z0) + dot4(qH, z1);
#pragma unroll
        for (int m = 32; m; m >>= 1) {
            s0 += __shfl_xor(s0, m, 64);
            s1 += __shfl_xor(s1, m, 64);
            s2 += __shfl_xor(s2, m, 64);
            s3 += __shfl_xor(s3, m, 64);
            s4 += __shfl_xor(s4, m, 64);
            s5 += __shfl_xor(s5, m, 64);
            s6 += __shfl_xor(s6, m, 64);
            s7 += __shfl_xor(s7, m, 64);
        }
        if (lane == 0) {
            const float phi_i = sm[512 + (row0 >> 8)];           // const over 8 rows
            const float4* PJ = (const float4*)(sm + 512);
            float4 pj0 = PJ[(row0 & 255) >> 2], pj1 = PJ[((row0 & 255) >> 2) + 1];
            float4 r0, r1;
            r0.x = (1.0f - GAMMA) * w0.x + GAMMA * (c0.x * phi_i * pj0.x + s0);
            r0.y = (1.0f - GAMMA) * w0.y + GAMMA * (c0.y * phi_i * pj0.y + s1);
            r0.z = (1.0f - GAMMA) * w0.z + GAMMA * (c0.z * phi_i * pj0.z + s2);
            r0.w = (1.0f - GAMMA) * w0.w + GAMMA * (c0.w * phi_i * pj0.w + s3);
            r1.x = (1.0f - GAMMA) * w1.x + GAMMA * (c1.x * phi_i * pj1.x + s4);
            r1.y = (1.0f - GAMMA) * w1.y + GAMMA * (c1.y * phi_i * pj1.y + s5);
            r1.z = (1.0f - GAMMA) * w1.z + GAMMA * (c1.z * phi_i * pj1.z + s6);
            r1.w = (1.0f - GAMMA) * w1.w + GAMMA * (c1.w * phi_i * pj1.w + s7);
            ((float4*)(out + NN + row0))[0] = r0;
            ((float4*)(out + NN + row0))[1] = r1;
        }
    }
}

extern "C" void kernel_launch(void* const* d_in, const int* in_sizes, int n_in,
                              void* d_out, int out_size, void* d_ws, size_t ws_size,
                              hipStream_t stream) {
    const float* I    = (const float*)d_in[0];
    const float* x    = (const float*)d_in[1];
    const float* W    = (const float*)d_in[2];
    const float* z    = (const float*)d_in[3];
    const float* C    = (const float*)d_in[4];
    const float* D    = (const float*)d_in[5];
    const float* F    = (const float*)d_in[6];
    const float* H    = (const float*)d_in[7];
    const float* Win1 = (const float*)d_in[8];
    const float* Win2 = (const float*)d_in[9];
    float* out = (float*)d_out;
    float* ws  = (float*)d_ws;   // ws[0:256]=phi_xn, ws[256:768]=psi_z (3 KB)

    hipLaunchKernelGGL(k_state, dim3(18), dim3(256), 0, stream,
                       I, x, W, z, Win1, out, ws);
    // 512 H-row blocks first (longest-running), then 2048 D blocks (32 rows each)
    hipLaunchKernelGGL(k_big, dim3(MM + (NN * NN) / 32), dim3(256), 0, stream,
                       W, C, D, F, H, Win2, I, z, ws, out);
}

// Round 3
// 284.019 us; speedup vs baseline: 1.1093x; 1.0458x over previous
//
#include <hip/hip_runtime.h>
#include <math.h>

#define GAMMA 0.1f
#define TAU   0.01f
#define NN    256
#define MM    512
#define KK    512

typedef float vf4 __attribute__((ext_vector_type(4)));

__device__ __forceinline__ float sigmoidf(float v) {
    return 1.0f / (1.0f + __expf(-v));
}
__device__ __forceinline__ float4 sigmoid4(float4 v) {
    return make_float4(sigmoidf(v.x), sigmoidf(v.y), sigmoidf(v.z), sigmoidf(v.w));
}
__device__ __forceinline__ float dot4(float4 a, float4 b) {
    return a.x * b.x + a.y * b.y + a.z * b.z + a.w * b.w;
}
// nontemporal float4 load (clang builtin needs ext_vector, not HIP struct)
__device__ __forceinline__ float4 ntload4(const float4* p) {
    vf4 v = __builtin_nontemporal_load((const vf4*)p);
    return make_float4(v.x, v.y, v.z, v.w);
}

// ---------------------------------------------------------------------------
// Kernel 1: x_new rows (blocks 0..15), psi_z = tanh(z) (blocks 16..17).
// ws[0:256] = phi_xn, ws[256:768] = psi_z.
// ---------------------------------------------------------------------------
__global__ __launch_bounds__(256) void k_state(
    const float* __restrict__ I, const float* __restrict__ x,
    const float* __restrict__ W, const float* __restrict__ z,
    const float* __restrict__ Win1,
    float* __restrict__ out, float* __restrict__ ws)
{
    const int b = blockIdx.x, t = threadIdx.x;
    if (b < 16) {
        const int wave = t >> 6, lane = t & 63;
        const int row0 = b * 16 + wave * 4;
        float4 xv = ((const float4*)x)[lane];
        float4 i0 = ((const float4*)I)[lane];
        float4 i1 = ((const float4*)I)[64 + lane];
        const float4* Wr = (const float4*)(W + row0 * NN);
        float4 w0 = Wr[lane], w1 = Wr[lane + 64], w2 = Wr[lane + 128], w3 = Wr[lane + 192];
        const float4* A = (const float4*)(Win1 + row0 * KK);
        float4 a0 = A[lane],       c0 = A[lane + 64];
        float4 a1 = A[lane + 128], c1 = A[lane + 192];
        float4 a2 = A[lane + 256], c2 = A[lane + 320];
        float4 a3 = A[lane + 384], c3 = A[lane + 448];
        float4 xo = ((const float4*)x)[row0 >> 2];

        float4 ph = sigmoid4(xv);
        float s0 = GAMMA * dot4(w0, ph) + dot4(a0, i0) + dot4(c0, i1);
        float s1 = GAMMA * dot4(w1, ph) + dot4(a1, i0) + dot4(c1, i1);
        float s2 = GAMMA * dot4(w2, ph) + dot4(a2, i0) + dot4(c2, i1);
        float s3 = GAMMA * dot4(w3, ph) + dot4(a3, i0) + dot4(c3, i1);
#pragma unroll
        for (int m = 32; m; m >>= 1) {
            s0 += __shfl_xor(s0, m, 64);
            s1 += __shfl_xor(s1, m, 64);
            s2 += __shfl_xor(s2, m, 64);
            s3 += __shfl_xor(s3, m, 64);
        }
        if (lane == 0) {
            float4 xn;
            xn.x = (1.0f - GAMMA) * xo.x + s0;
            xn.y = (1.0f - GAMMA) * xo.y + s1;
            xn.z = (1.0f - GAMMA) * xo.z + s2;
            xn.w = (1.0f - GAMMA) * xo.w + s3;
            ((float4*)out)[row0 >> 2] = xn;
            ((float4*)ws)[row0 >> 2] = sigmoid4(xn);
        }
    } else {
        const int idx = (b - 16) * 256 + t;
        ws[NN + idx] = tanhf(z[idx]);
    }
}

// ---------------------------------------------------------------------------
// k_H: z_new. 512 blocks x 1024 threads, one H row (256 KB) per block.
// Normal (cached) loads — A/B control vs k_D's nontemporal.
// ---------------------------------------------------------------------------
__global__ __launch_bounds__(1024, 4) void k_H(
    const float* __restrict__ H, const float* __restrict__ Win2,
    const float* __restrict__ I, const float* __restrict__ z,
    const float* __restrict__ F, const float* __restrict__ ws,
    float* __restrict__ out)
{
    __shared__ float sm[256];
    __shared__ float red[16];
    const int b = blockIdx.x, t = threadIdx.x;
    if (t < 64) ((float4*)sm)[t] = ((const float4*)ws)[t];       // phi_xn
    float wi = 0.0f;
    if (t < KK) wi = Win2[(size_t)b * KK + t] * I[t];            // W_in_2 @ I part
    __syncthreads();
    const float4* H4 = (const float4*)(H + (size_t)b * (NN * NN));
    const float4 pj = ((const float4*)sm)[t & 63];
    const int i0 = t >> 6;                                       // + 16q per iter
    float a0 = wi, a1 = 0.0f, a2 = 0.0f, a3 = 0.0f;
#pragma unroll
    for (int qq = 0; qq < 2; ++qq) {
        float4 h[8];
        float  pi[8];
#pragma unroll
        for (int u = 0; u < 8; ++u) {                            // 8 loads in flight
            const int q = qq * 8 + u;
            h[u]  = H4[t + 1024 * q];
            pi[u] = sm[i0 + 16 * q];
        }
#pragma unroll
        for (int u = 0; u < 8; ++u) {                            // 4 indep fp chains
            const float term = pi[u] * dot4(h[u], pj);
            if      ((u & 3) == 0) a0 += term;
            else if ((u & 3) == 1) a1 += term;
            else if ((u & 3) == 2) a2 += term;
            else                   a3 += term;
        }
    }
    float acc = (a0 + a1) + (a2 + a3);
#pragma unroll
    for (int m = 32; m; m >>= 1) acc += __shfl_xor(acc, m, 64);
    if ((t & 63) == 0) red[t >> 6] = acc;
    __syncthreads();
    if (t < 64) {
        float v = (t < 16) ? red[t] : 0.0f;
#pragma unroll
        for (int m = 8; m; m >>= 1) v += __shfl_xor(v, m, 64);
        if (t == 0) {
            const float gt = GAMMA * TAU;
            float zn = (1.0f - gt) * z[b] + gt * (F[b] * ws[NN + b] + v);
            out[NN + NN * NN + b] = zn;
        }
    }
}

// ---------------------------------------------------------------------------
// k_D: W_new. 1024 blocks x 256 threads; wave-per-row, 16 rows/wave,
// depth-2 software pipeline, NONTEMPORAL loads on D, coalesced 16-row store.
// ---------------------------------------------------------------------------
__global__ __launch_bounds__(256) void k_D(
    const float* __restrict__ W, const float* __restrict__ Cv,
    const float* __restrict__ D, const float* __restrict__ ws,
    float* __restrict__ out)
{
    __shared__ float sm[768];   // [0:512)=psi_z, [512:768)=phi_xn
    const int t = threadIdx.x;
    if (t < 128)      ((float4*)sm)[t] = ((const float4*)(ws + NN))[t];
    else if (t < 192) ((float4*)sm)[t] = ((const float4*)ws)[t - 128];
    __syncthreads();
    const int wave = t >> 6, lane = t & 63;
    const float4 z0 = ((const float4*)sm)[lane];
    const float4 z1 = ((const float4*)sm)[64 + lane];
    const int row0 = blockIdx.x * 64 + wave * 16;
    const float4* R = (const float4*)(D + (size_t)row0 * MM);    // 128 f4/row

    // epilogue operands for lanes 0..15 (coalesced) + wave-uniform phi_i
    float wrow = 0.0f, crow = 0.0f, pjrow = 0.0f;
    if (lane < 16) {
        wrow  = W[row0 + lane];
        crow  = Cv[row0 + lane];
        pjrow = sm[512 + (row0 & 255) + lane];
    }
    const float pi = sm[512 + (row0 >> 8)];

    // depth-2 pipelined row loop (rows r and r+1 in flight while reducing)
    float4 fa0 = ntload4(&R[lane]),        fb0 = ntload4(&R[lane + 64]);
    float4 fa1 = ntload4(&R[lane + 128]),  fb1 = ntload4(&R[lane + 192]);
    float keep = 0.0f;
#pragma unroll
    for (int r = 0; r < 16; ++r) {
        float4 ca, cb;
        if (r & 1) { ca = fa1; cb = fb1; } else { ca = fa0; cb = fb0; }
        if (r + 2 < 16) {
            const float4* Rn = R + (r + 2) * 128;
            if (r & 1) { fa1 = ntload4(&Rn[lane]); fb1 = ntload4(&Rn[lane + 64]); }
            else       { fa0 = ntload4(&Rn[lane]); fb0 = ntload4(&Rn[lane + 64]); }
        }
        float s = dot4(ca, z0) + dot4(cb, z1);
#pragma unroll
        for (int m = 32; m; m >>= 1) s += __shfl_xor(s, m, 64);
        if (lane == r) keep = s;           // butterfly leaves sum on all lanes
    }
    if (lane < 16) {                        // coalesced 64 B store per wave
        float wn = (1.0f - GAMMA) * wrow + GAMMA * (crow * pi * pjrow + keep);
        out[NN + row0 + lane] = wn;
    }
}

extern "C" void kernel_launch(void* const* d_in, const int* in_sizes, int n_in,
                              void* d_out, int out_size, void* d_ws, size_t ws_size,
                              hipStream_t stream) {
    const float* I    = (const float*)d_in[0];
    const float* x    = (const float*)d_in[1];
    const float* W    = (const float*)d_in[2];
    const float* z    = (const float*)d_in[3];
    const float* C    = (const float*)d_in[4];
    const float* D    = (const float*)d_in[5];
    const float* F    = (const float*)d_in[6];
    const float* H    = (const float*)d_in[7];
    const float* Win1 = (const float*)d_in[8];
    const float* Win2 = (const float*)d_in[9];
    float* out = (float*)d_out;
    float* ws  = (float*)d_ws;   // ws[0:256]=phi_xn, ws[256:768]=psi_z

    hipLaunchKernelGGL(k_state, dim3(18), dim3(256), 0, stream,
                       I, x, W, z, Win1, out, ws);
    hipLaunchKernelGGL(k_H, dim3(MM), dim3(1024), 0, stream,
                       H, Win2, I, z, F, ws, out);
    hipLaunchKernelGGL(k_D, dim3((NN * NN) / 64), dim3(256), 0, stream,
                       W, C, D, ws, out);
}

// Round 4
// 272.693 us; speedup vs baseline: 1.1554x; 1.0415x over previous
//
#include <hip/hip_runtime.h>
#include <math.h>

#define GAMMA 0.1f
#define TAU   0.01f
#define NN    256
#define MM    512
#define KK    512

typedef float vf4 __attribute__((ext_vector_type(4)));

__device__ __forceinline__ float sigmoidf(float v) {
    return 1.0f / (1.0f + __expf(-v));
}
__device__ __forceinline__ float4 sigmoid4(float4 v) {
    return make_float4(sigmoidf(v.x), sigmoidf(v.y), sigmoidf(v.z), sigmoidf(v.w));
}
__device__ __forceinline__ float dot4(float4 a, float4 b) {
    return a.x * b.x + a.y * b.y + a.z * b.z + a.w * b.w;
}
__device__ __forceinline__ float4 ntload4(const float4* p) {
    vf4 v = __builtin_nontemporal_load((const vf4*)p);
    return make_float4(v.x, v.y, v.z, v.w);
}

// ---------------------------------------------------------------------------
// Kernel 1: x_new rows (blocks 0..15), psi_z = tanh(z) (blocks 16..17).
// ws[0:256] = phi_xn, ws[256:768] = psi_z.
// ---------------------------------------------------------------------------
__global__ __launch_bounds__(256) void k_state(
    const float* __restrict__ I, const float* __restrict__ x,
    const float* __restrict__ W, const float* __restrict__ z,
    const float* __restrict__ Win1,
    float* __restrict__ out, float* __restrict__ ws)
{
    const int b = blockIdx.x, t = threadIdx.x;
    if (b < 16) {
        const int wave = t >> 6, lane = t & 63;
        const int row0 = b * 16 + wave * 4;
        float4 xv = ((const float4*)x)[lane];
        float4 i0 = ((const float4*)I)[lane];
        float4 i1 = ((const float4*)I)[64 + lane];
        const float4* Wr = (const float4*)(W + row0 * NN);
        float4 w0 = Wr[lane], w1 = Wr[lane + 64], w2 = Wr[lane + 128], w3 = Wr[lane + 192];
        const float4* A = (const float4*)(Win1 + row0 * KK);
        float4 a0 = A[lane],       c0 = A[lane + 64];
        float4 a1 = A[lane + 128], c1 = A[lane + 192];
        float4 a2 = A[lane + 256], c2 = A[lane + 320];
        float4 a3 = A[lane + 384], c3 = A[lane + 448];
        float4 xo = ((const float4*)x)[row0 >> 2];

        float4 ph = sigmoid4(xv);
        float s0 = GAMMA * dot4(w0, ph) + dot4(a0, i0) + dot4(c0, i1);
        float s1 = GAMMA * dot4(w1, ph) + dot4(a1, i0) + dot4(c1, i1);
        float s2 = GAMMA * dot4(w2, ph) + dot4(a2, i0) + dot4(c2, i1);
        float s3 = GAMMA * dot4(w3, ph) + dot4(a3, i0) + dot4(c3, i1);
#pragma unroll
        for (int m = 32; m; m >>= 1) {
            s0 += __shfl_xor(s0, m, 64);
            s1 += __shfl_xor(s1, m, 64);
            s2 += __shfl_xor(s2, m, 64);
            s3 += __shfl_xor(s3, m, 64);
        }
        if (lane == 0) {
            float4 xn;
            xn.x = (1.0f - GAMMA) * xo.x + s0;
            xn.y = (1.0f - GAMMA) * xo.y + s1;
            xn.z = (1.0f - GAMMA) * xo.z + s2;
            xn.w = (1.0f - GAMMA) * xo.w + s3;
            ((float4*)out)[row0 >> 2] = xn;
            ((float4*)ws)[row0 >> 2] = sigmoid4(xn);
        }
    } else {
        const int idx = (b - 16) * 256 + t;
        ws[NN + idx] = tanhf(z[idx]);
    }
}

// ---------------------------------------------------------------------------
// k_WZ (fused): 1536 blocks x 256 threads.
//   b % 3 == 0  -> H phase: z_new row (b/3): full 256 KB row, 64 f4/thread.
//   else        -> D phase: 64 W_new rows, wave handles 16 rows (32 KB stream,
//                  register partials, single end-of-stream reduction).
// ws: [0:256]=phi_xn, [256:768]=psi_z.
// ---------------------------------------------------------------------------
__global__ __launch_bounds__(256, 4) void k_WZ(
    const float* __restrict__ W, const float* __restrict__ Cv,
    const float* __restrict__ D, const float* __restrict__ F,
    const float* __restrict__ H, const float* __restrict__ Win2,
    const float* __restrict__ I, const float* __restrict__ z,
    const float* __restrict__ ws, float* __restrict__ out)
{
    __shared__ float sm[768];   // [0:512)=psi_z, [512:768)=phi_xn
    __shared__ float red[4];
    const int b = blockIdx.x, t = threadIdx.x;
    const int wave = t >> 6, lane = t & 63;

    if (t < 128)      ((float4*)sm)[t] = ((const float4*)(ws + NN))[t];  // psi_z
    else if (t < 192) ((float4*)sm)[t] = ((const float4*)ws)[t - 128];   // phi_xn

    if (b % 3 == 0) {
        // ================= H phase: one z row =================
        const int row = b / 3;                         // 0..511
        float wi = Win2[(size_t)row * KK + t] * I[t]
                 + Win2[(size_t)row * KK + 256 + t] * I[256 + t];
        __syncthreads();
        const float4* H4 = (const float4*)(H + (size_t)row * (NN * NN));
        const float* phi = sm + 512;
        const float4 pj = ((const float4*)phi)[t & 63];
        float a0 = wi, a1 = 0.0f, a2 = 0.0f, a3 = 0.0f;
        float4 buf[2][8];
#pragma unroll
        for (int u = 0; u < 8; ++u) buf[0][u] = ntload4(&H4[t + 256 * u]);
#pragma unroll
        for (int g = 0; g < 8; ++g) {
            const int cur = g & 1, nxt = cur ^ 1;
            if (g < 7) {
#pragma unroll
                for (int u = 0; u < 8; ++u)
                    buf[nxt][u] = ntload4(&H4[t + 256 * ((g + 1) * 8 + u)]);
            }
#pragma unroll
            for (int u = 0; u < 8; ++u) {
                const float term = phi[wave + 4 * (g * 8 + u)] * dot4(buf[cur][u], pj);
                if      ((u & 3) == 0) a0 += term;
                else if ((u & 3) == 1) a1 += term;
                else if ((u & 3) == 2) a2 += term;
                else                   a3 += term;
            }
        }
        float acc = (a0 + a1) + (a2 + a3);
#pragma unroll
        for (int m = 32; m; m >>= 1) acc += __shfl_xor(acc, m, 64);
        if (lane == 0) red[wave] = acc;
        __syncthreads();
        if (t == 0) {
            const float gt = GAMMA * TAU;
            float tot = red[0] + red[1] + red[2] + red[3];
            float zn = (1.0f - gt) * z[row] + gt * (F[row] * ws[NN + row] + tot);
            out[NN + NN * NN + row] = zn;
        }
    } else {
        // ================= D phase: 16 rows per wave =================
        const int d = b - b / 3 - 1;                   // 0..1023
        const int row0 = d * 64 + wave * 16;
        const float4* R = (const float4*)(D + (size_t)row0 * MM);  // 128 f4/row
        // epilogue operands early (tiny, coalesced)
        float wrow = 0.0f, crow = 0.0f;
        if (lane < 16) { wrow = W[row0 + lane]; crow = Cv[row0 + lane]; }
        __syncthreads();
        const float4 z0 = ((const float4*)sm)[lane];
        const float4 z1 = ((const float4*)sm)[64 + lane];

        float p[16];
        float4 A[2][4], B[2][4];
#pragma unroll
        for (int r = 0; r < 4; ++r) {
            A[0][r] = ntload4(&R[lane + 128 * r]);
            B[0][r] = ntload4(&R[lane + 64 + 128 * r]);
        }
#pragma unroll
        for (int g = 0; g < 4; ++g) {
            const int cur = g & 1, nxt = cur ^ 1;
            if (g < 3) {
#pragma unroll
                for (int r = 0; r < 4; ++r) {
                    A[nxt][r] = ntload4(&R[lane + 128 * ((g + 1) * 4 + r)]);
                    B[nxt][r] = ntload4(&R[lane + 64 + 128 * ((g + 1) * 4 + r)]);
                }
            }
#pragma unroll
            for (int r = 0; r < 4; ++r)
                p[g * 4 + r] = dot4(A[cur][r], z0) + dot4(B[cur][r], z1);
        }
        // 16 independent butterflies, fully interleaved (once per 32 KB stream)
#pragma unroll
        for (int m = 32; m; m >>= 1) {
#pragma unroll
            for (int r = 0; r < 16; ++r) p[r] += __shfl_xor(p[r], m, 64);
        }
        float keep = 0.0f;
#pragma unroll
        for (int r = 0; r < 16; ++r) if (lane == r) keep = p[r];
        if (lane < 16) {
            const float phi_i = sm[512 + ((row0 + lane) >> 8)];
            const float phi_j = sm[512 + ((row0 + lane) & 255)];
            float wn = (1.0f - GAMMA) * wrow + GAMMA * (crow * phi_i * phi_j + keep);
            out[NN + row0 + lane] = wn;
        }
    }
}

extern "C" void kernel_launch(void* const* d_in, const int* in_sizes, int n_in,
                              void* d_out, int out_size, void* d_ws, size_t ws_size,
                              hipStream_t stream) {
    const float* I    = (const float*)d_in[0];
    const float* x    = (const float*)d_in[1];
    const float* W    = (const float*)d_in[2];
    const float* z    = (const float*)d_in[3];
    const float* C    = (const float*)d_in[4];
    const float* D    = (const float*)d_in[5];
    const float* F    = (const float*)d_in[6];
    const float* H    = (const float*)d_in[7];
    const float* Win1 = (const float*)d_in[8];
    const float* Win2 = (const float*)d_in[9];
    float* out = (float*)d_out;
    float* ws  = (float*)d_ws;   // ws[0:256]=phi_xn, ws[256:768]=psi_z

    hipLaunchKernelGGL(k_state, dim3(18), dim3(256), 0, stream,
                       I, x, W, z, Win1, out, ws);
    // 1536 blocks: every 3rd is an H(z) row block; others cover 64 D rows each
    hipLaunchKernelGGL(k_WZ, dim3(1536), dim3(256), 0, stream,
                       W, C, D, F, H, Win2, I, z, ws, out);
}